// Round 14
// baseline (223.287 us; speedup 1.0000x reference)
//
#include <hip/hip_runtime.h>

#define KNN    8
#define BLOCK  256
#define TILE   2048
#define GD     32              // grid cells per axis
#define NC     (GD*GD*GD)      // 32768 cells
#define EPSW   1e-8f
#define BIGF   3.4e38f

// Sorted-descending top-8 insert; all indices compile-time -> stays in VGPRs.
// REQUIRES bd sorted descending (bd[0] = current max); preserves that invariant.
__device__ __forceinline__ void insert8(float d2, int j, float bd[KNN], int bi[KNN]) {
    if (d2 < bd[0]) {
        bd[0] = d2; bi[0] = j;
#pragma unroll
        for (int t = 0; t < KNN - 1; t++) {
            if (bd[t] < bd[t + 1]) {
                float td = bd[t]; bd[t] = bd[t + 1]; bd[t + 1] = td;
                int   ti = bi[t]; bi[t] = bi[t + 1]; bi[t + 1] = ti;
            }
        }
    }
}

// Compare-exchange, descending (a keeps max), with index payload.
__device__ __forceinline__ void ced(float& a, int& ai, float& b, int& bi) {
    if (a < b) { float t = a; a = b; b = t; int ti = ai; ai = bi; bi = ti; }
}
// Sort a bitonic 8-seq descending (3 half-cleaner stages), with payload.
__device__ __forceinline__ void sort8_desc(float d[KNN], int ix[KNN]) {
    ced(d[0],ix[0],d[4],ix[4]); ced(d[1],ix[1],d[5],ix[5]);
    ced(d[2],ix[2],d[6],ix[6]); ced(d[3],ix[3],d[7],ix[7]);
    ced(d[0],ix[0],d[2],ix[2]); ced(d[1],ix[1],d[3],ix[3]);
    ced(d[4],ix[4],d[6],ix[6]); ced(d[5],ix[5],d[7],ix[7]);
    ced(d[0],ix[0],d[1],ix[1]); ced(d[2],ix[2],d[3],ix[3]);
    ced(d[4],ix[4],d[5],ix[5]); ced(d[6],ix[6],d[7],ix[7]);
}
// Merge with partner lane (xor mask): keep the 8 smallest of my-desc-sorted
// list and partner's desc-sorted list (bitonic half-cleaner: C[i]=min(A[i],B[7-i])).
// Both partners compute the identical merged list. Result bitonic; sort if chaining
// OR if insert8 will be applied afterwards (insert8 requires sorted input!).
__device__ __forceinline__ void merge_lists(float bd[KNN], int bi[KNN], int mask, bool sort_after) {
    float pd[KNN]; int pi[KNN];
#pragma unroll
    for (int j = 0; j < KNN; j++) { pd[j] = __shfl_xor(bd[j], mask); pi[j] = __shfl_xor(bi[j], mask); }
#pragma unroll
    for (int j = 0; j < KNN; j++) {
        if (pd[KNN - 1 - j] < bd[j]) { bd[j] = pd[KNN - 1 - j]; bi[j] = pi[KNN - 1 - j]; }
    }
    if (sort_after) sort8_desc(bd, bi);
}
// Exact 8th-smallest over the 4 lanes of a quad (distances only, temps; does
// NOT modify bd). All 4 lanes return the same value.
__device__ __forceinline__ float merged_thr4(const float bd[KNN]) {
    float c[KNN], p[KNN];
#pragma unroll
    for (int j = 0; j < KNN; j++) c[j] = bd[j];
#pragma unroll
    for (int j = 0; j < KNN; j++) p[j] = __shfl_xor(c[j], 1);
#pragma unroll
    for (int j = 0; j < KNN; j++) c[j] = fminf(c[j], p[KNN - 1 - j]);
    // sort bitonic desc (no payload)
    {
        float mx, mn;
        mx = fmaxf(c[0],c[4]); mn = fminf(c[0],c[4]); c[0]=mx; c[4]=mn;
        mx = fmaxf(c[1],c[5]); mn = fminf(c[1],c[5]); c[1]=mx; c[5]=mn;
        mx = fmaxf(c[2],c[6]); mn = fminf(c[2],c[6]); c[2]=mx; c[6]=mn;
        mx = fmaxf(c[3],c[7]); mn = fminf(c[3],c[7]); c[3]=mx; c[7]=mn;
        mx = fmaxf(c[0],c[2]); mn = fminf(c[0],c[2]); c[0]=mx; c[2]=mn;
        mx = fmaxf(c[1],c[3]); mn = fminf(c[1],c[3]); c[1]=mx; c[3]=mn;
        mx = fmaxf(c[4],c[6]); mn = fminf(c[4],c[6]); c[4]=mx; c[6]=mn;
        mx = fmaxf(c[5],c[7]); mn = fminf(c[5],c[7]); c[5]=mx; c[7]=mn;
        mx = fmaxf(c[0],c[1]); mn = fminf(c[0],c[1]); c[0]=mx; c[1]=mn;
        mx = fmaxf(c[2],c[3]); mn = fminf(c[2],c[3]); c[2]=mx; c[3]=mn;
        mx = fmaxf(c[4],c[5]); mn = fminf(c[4],c[5]); c[4]=mx; c[5]=mn;
        mx = fmaxf(c[6],c[7]); mn = fminf(c[6],c[7]); c[6]=mx; c[7]=mn;
    }
#pragma unroll
    for (int j = 0; j < KNN; j++) p[j] = __shfl_xor(c[j], 2);
#pragma unroll
    for (int j = 0; j < KNN; j++) c[j] = fminf(c[j], p[KNN - 1 - j]);
    float m = c[0];
#pragma unroll
    for (int j = 1; j < KNN; j++) m = fmaxf(m, c[j]);
    return m;
}

// Order-preserving float <-> uint for atomic min.
__device__ __forceinline__ unsigned fenc(float f) {
    unsigned u = __float_as_uint(f);
    return (u & 0x80000000u) ? ~u : (u | 0x80000000u);
}
__device__ __forceinline__ float fdec(unsigned e) {
    unsigned u = (e & 0x80000000u) ? (e ^ 0x80000000u) : ~e;
    return __uint_as_float(u);
}

// bbw[0..2] = enc(min), bbw[3..5] = enc(-max)  -> ALL init to 0xFFFFFFFF,
// ALL updated with atomicMin (one memset, one atomic op type).
__device__ __forceinline__ void load_bb(const unsigned* __restrict__ bbw,
                                        float mn[3], float inv[3], float& hmin) {
    hmin = BIGF;
#pragma unroll
    for (int a = 0; a < 3; a++) {
        float lo = fdec(bbw[a]), hi = -fdec(bbw[3 + a]);
        float w = fmaxf(hi - lo, 1e-9f);
        mn[a] = lo;
        inv[a] = (float)GD / w;
        hmin = fminf(hmin, w / (float)GD);
    }
}

__device__ __forceinline__ int cell_clamp(int c) {
    return c < 0 ? 0 : (c > GD - 1 ? GD - 1 : c);
}

// ---------------- grid build ----------------

// Fused: zero counter region (rcur,qcur,pcnt) + multi-block bbox over refs.
__global__ __launch_bounds__(256) void bbox_zero(const float* __restrict__ r, int M,
                                                 unsigned* __restrict__ bbw,
                                                 int* __restrict__ zbase, int zcount) {
    int idx = blockIdx.x * 256 + threadIdx.x;
    for (int j = idx; j < zcount; j += gridDim.x * 256) zbase[j] = 0;
    float mn0 = BIGF, mn1 = BIGF, mn2 = BIGF;
    float mx0 = -BIGF, mx1 = -BIGF, mx2 = -BIGF;
    for (int j = idx; j < M; j += gridDim.x * 256) {
        float x = r[3 * j], y = r[3 * j + 1], z = r[3 * j + 2];
        mn0 = fminf(mn0, x); mx0 = fmaxf(mx0, x);
        mn1 = fminf(mn1, y); mx1 = fmaxf(mx1, y);
        mn2 = fminf(mn2, z); mx2 = fmaxf(mx2, z);
    }
#pragma unroll
    for (int o = 32; o > 0; o >>= 1) {
        mn0 = fminf(mn0, __shfl_xor(mn0, o));
        mn1 = fminf(mn1, __shfl_xor(mn1, o));
        mn2 = fminf(mn2, __shfl_xor(mn2, o));
        mx0 = fmaxf(mx0, __shfl_xor(mx0, o));
        mx1 = fmaxf(mx1, __shfl_xor(mx1, o));
        mx2 = fmaxf(mx2, __shfl_xor(mx2, o));
    }
    if ((threadIdx.x & 63) == 0) {
        atomicMin(bbw + 0, fenc(mn0)); atomicMin(bbw + 1, fenc(mn1)); atomicMin(bbw + 2, fenc(mn2));
        atomicMin(bbw + 3, fenc(-mx0)); atomicMin(bbw + 4, fenc(-mx1)); atomicMin(bbw + 5, fenc(-mx2));
    }
}

// Histogram refs AND queries in one dispatch (items 0..M-1 = refs, M..M+N-1 = queries).
__global__ __launch_bounds__(256) void hist2(const float* __restrict__ r,
                                             const float* __restrict__ q,
                                             int M, int N, const unsigned* __restrict__ bbw,
                                             int* __restrict__ rcid, int* __restrict__ qcid,
                                             int* __restrict__ rcnt, int* __restrict__ qcnt) {
    float mn[3], inv[3], hmin;
    load_bb(bbw, mn, inv, hmin);
    int i = blockIdx.x * 256 + threadIdx.x;
    if (i < M) {
        int cx = cell_clamp((int)((r[3 * i]     - mn[0]) * inv[0]));
        int cy = cell_clamp((int)((r[3 * i + 1] - mn[1]) * inv[1]));
        int cz = cell_clamp((int)((r[3 * i + 2] - mn[2]) * inv[2]));
        int cid = (cz * GD + cy) * GD + cx;
        rcid[i] = cid;
        atomicAdd(rcnt + cid, 1);
    } else if (i < M + N) {
        int j = i - M;
        int cx = cell_clamp((int)((q[3 * j]     - mn[0]) * inv[0]));
        int cy = cell_clamp((int)((q[3 * j + 1] - mn[1]) * inv[1]));
        int cz = cell_clamp((int)((q[3 * j + 2] - mn[2]) * inv[2]));
        int cid = (cz * GD + cy) * GD + cx;
        qcid[j] = cid;
        atomicAdd(qcnt + cid, 1);
    }
}

// Exclusive scan of NC cell counts; block 0 -> refs, block 1 -> queries.
__global__ __launch_bounds__(1024) void scan2(int* __restrict__ rcnt, int* __restrict__ rstart,
                                              int* __restrict__ qcnt, int* __restrict__ qstart) {
    int* cnt = (blockIdx.x == 0) ? rcnt : qcnt;
    int* st  = (blockIdx.x == 0) ? rstart : qstart;
    __shared__ int part[1024];
    int t = threadIdx.x;
    int base = t * 32;
    int s = 0;
#pragma unroll
    for (int k = 0; k < 32; k++) s += cnt[base + k];
    part[t] = s;
    __syncthreads();
    for (int off = 1; off < 1024; off <<= 1) {
        int v = (t >= off) ? part[t - off] : 0;
        __syncthreads();
        part[t] += v;
        __syncthreads();
    }
    int run = part[t] - s;
#pragma unroll
    for (int k = 0; k < 32; k++) {
        int c = cnt[base + k];
        st[base + k] = run;
        cnt[base + k] = run;         // cursor = start
        run += c;
    }
    if (t == 1023) st[NC] = run;
}

// Scatter refs into cell-sorted packed float4 (x,y,z,|r|^2) + orig-index map;
// scatter queries into cell-sorted packed float4 (x,y,z,|q|^2) + orig-index
// order (PRE-GATHER: pass1 then reads qps[g] coalesced, no scattered q loads).
__global__ __launch_bounds__(256) void scatter2(const float* __restrict__ r,
                                                const float* __restrict__ q, int M, int N,
                                                const int* __restrict__ rcid,
                                                const int* __restrict__ qcid,
                                                int* __restrict__ rcur, int* __restrict__ qcur,
                                                float4* __restrict__ rps, int* __restrict__ sidx,
                                                float4* __restrict__ qps, int* __restrict__ qorder) {
    int i = blockIdx.x * 256 + threadIdx.x;
    if (i < M) {
        int pos = atomicAdd(rcur + rcid[i], 1);
        float x = r[3 * i], y = r[3 * i + 1], z = r[3 * i + 2];
        rps[pos] = make_float4(x, y, z, x * x + y * y + z * z);
        sidx[pos] = i;
    } else if (i < M + N) {
        int j = i - M;
        int pos = atomicAdd(qcur + qcid[j], 1);
        float x = q[3 * j], y = q[3 * j + 1], z = q[3 * j + 2];
        qps[pos] = make_float4(x, y, z, x * x + y * y + z * z);
        qorder[pos] = j;
    }
}

// Scan a Chebyshev shell at ring R (quad-cooperative: this lane takes points
// ii = s+sub, s+sub+4, ...). x-contiguous rows collapse to one range scan.
__device__ __forceinline__ void scan_shell(
    int R, int cx, int cy, int cz, int sub,
    const float4* __restrict__ rps, const int* __restrict__ rstart,
    float qx, float qy, float qz, float q2,
    float bd[KNN], int bi[KNN], float& thr) {
    for (int dz = -R; dz <= R; ++dz) {
        int z = cz + dz;
        if ((unsigned)z >= GD) continue;
        for (int dy = -R; dy <= R; ++dy) {
            int y = cy + dy;
            if ((unsigned)y >= GD) continue;
            int rowb = (z * GD + y) * GD;
            if (dz == -R || dz == R || dy == -R || dy == R) {
                int x0 = max(cx - R, 0), x1 = min(cx + R, GD - 1);
                int s = rstart[rowb + x0], e = rstart[rowb + x1 + 1];
                for (int ii = s + sub; ii < e; ii += 4) {
                    float4 p = rps[ii];
                    float d2 = (q2 + p.w) - 2.0f * (qx * p.x + qy * p.y + qz * p.z);
                    if (d2 < thr) { insert8(d2, ii, bd, bi); thr = bd[0]; }
                }
            } else {
                int xl = cx - R, xr = cx + R;
                if (xl >= 0) {
                    int s = rstart[rowb + xl], e = rstart[rowb + xl + 1];
                    for (int ii = s + sub; ii < e; ii += 4) {
                        float4 p = rps[ii];
                        float d2 = (q2 + p.w) - 2.0f * (qx * p.x + qy * p.y + qz * p.z);
                        if (d2 < thr) { insert8(d2, ii, bd, bi); thr = bd[0]; }
                    }
                }
                if (xr < GD) {
                    int s = rstart[rowb + xr], e = rstart[rowb + xr + 1];
                    for (int ii = s + sub; ii < e; ii += 4) {
                        float4 p = rps[ii];
                        float d2 = (q2 + p.w) - 2.0f * (qx * p.x + qy * p.y + qz * p.z);
                        if (d2 < thr) { insert8(d2, ii, bd, bi); thr = bd[0]; }
                    }
                }
            }
        }
    }
}

// ---------------- pass 1: 4 lanes per query, rings 0..2 ONLY ----------------
// Lanes split each point stream mod 4 (disjoint -> duplicate-free union).
// Termination bound: EXACT merged 8th-smallest over the quad (merged_thr4).
// Query coords come from the PRE-GATHERED qps[] (coalesced). After rings 0..R,
// unscanned cells are >= R*hmin away (valid for bbox-clamped queries since
// refs are never clamped). Ring 3 is DELIBERATELY NOT scanned here: the ~2%
// of queries not terminated by the ring-2 bound are the latency-dominating
// stragglers (they run at ~1 wave/CU after most waves retire). They go to
// pass 2, whose block-per-query structure is latency-tolerant (~0.8 us/query
// round at 512 blocks).
__global__ __launch_bounds__(256) void knn_pass1(
    const float4* __restrict__ rps, const int* __restrict__ rstart,
    const float4* __restrict__ qps, const int* __restrict__ qorder,
    const int* __restrict__ sidx, const float* __restrict__ f,
    const unsigned* __restrict__ bbw, float* __restrict__ out,
    int* __restrict__ pend, int* __restrict__ pcnt, int N) {
    int t = blockIdx.x * 256 + threadIdx.x;
    int g = t >> 2;                 // query-group id
    int sub = t & 3;
    if (g >= N) return;
    int qi = qorder[g];             // independent load; needed only at the end
    float4 qp = qps[g];             // coalesced/broadcast 16B
    float qx = qp.x, qy = qp.y, qz = qp.z, q2 = qp.w;
    float mn[3], inv[3], hmin;
    load_bb(bbw, mn, inv, hmin);
    int cx = cell_clamp((int)((qx - mn[0]) * inv[0]));
    int cy = cell_clamp((int)((qy - mn[1]) * inv[1]));
    int cz = cell_clamp((int)((qz - mn[2]) * inv[2]));

    float bd[KNN]; int bi[KNN];
#pragma unroll
    for (int k = 0; k < KNN; k++) { bd[k] = BIGF; bi[k] = 0; }
    float thr = BIGF;

    // --- rings 0..1 as nine full rows; all 9 range pairs hoisted (independent loads) ---
    int rs[9], re[9];
#pragma unroll
    for (int dz = -1; dz <= 1; dz++) {
#pragma unroll
        for (int dy = -1; dy <= 1; dy++) {
            int k = (dz + 1) * 3 + (dy + 1);
            int z = cz + dz, y = cy + dy;
            if ((unsigned)z >= GD || (unsigned)y >= GD) { rs[k] = 0; re[k] = 0; }
            else {
                int rowb = (z * GD + y) * GD;
                int x0 = max(cx - 1, 0), x1 = min(cx + 1, GD - 1);
                rs[k] = rstart[rowb + x0]; re[k] = rstart[rowb + x1 + 1];
            }
        }
    }
#pragma unroll
    for (int k = 0; k < 9; k++) {
        for (int ii = rs[k] + sub; ii < re[k]; ii += 4) {
            float4 p = rps[ii];
            float d2 = (q2 + p.w) - 2.0f * (qx * p.x + qy * p.y + qz * p.z);
            if (d2 < thr) { insert8(d2, ii, bd, bi); thr = bd[0]; }
        }
    }
    float mthr = merged_thr4(bd);
    thr = fminf(thr, mthr);
    bool done = (mthr <= hmin * hmin);

    if (!done) {
        scan_shell(2, cx, cy, cz, sub, rps, rstart, qx, qy, qz, q2, bd, bi, thr);
        mthr = merged_thr4(bd);
        done = (mthr <= 4.0f * hmin * hmin);
    }

    if (!done) {
        if (sub == 0) { int pos = atomicAdd(pcnt, 1); pend[pos] = qi; }
        return;
    }

    // exact merge of the quad's 4 disjoint lists -> global top-8 (order-free for IDW)
    merge_lists(bd, bi, 1, true);
    merge_lists(bd, bi, 2, false);
    if (sub == 0) {
        float wsum = 0.f, ox = 0.f, oy = 0.f, oz = 0.f;
#pragma unroll
        for (int k = 0; k < KNN; k++) {
            float w = 1.0f / (fmaxf(bd[k], 0.0f) + EPSW);
            int j = sidx[bi[k]];
            wsum += w;
            ox += w * f[3 * j];
            oy += w * f[3 * j + 1];
            oz += w * f[3 * j + 2];
        }
        float invw = 1.0f / wsum;
        out[3 * qi]     = ox * invw;
        out[3 * qi + 1] = oy * invw;
        out[3 * qi + 2] = oz * invw;
    }
}

// ---------------- pass 2: BLOCK-per-query exact brute force ----------------
// 256 threads share one pending query: each scans M/256 candidates 8-deep
// pipelined, wave-internal bitonic merge (FINAL MERGE SORTED: insert8 follows),
// 4-entry cross-wave LDS merge by tid 0.
__global__ __launch_bounds__(256) void knn_pass2(
    const float4* __restrict__ rps, const int* __restrict__ pend,
    const int* __restrict__ pcnt, const float* __restrict__ q,
    const int* __restrict__ sidx, const float* __restrict__ f,
    float* __restrict__ out, int M) {
    __shared__ float sd[4][KNN];
    __shared__ int   si[4][KNN];
    int tid = threadIdx.x;
    int lane = tid & 63, wv = tid >> 6;
    int cnt = *pcnt;
    for (int w = blockIdx.x; w < cnt; w += gridDim.x) {
        int qi = pend[w];
        float qx = q[3 * qi], qy = q[3 * qi + 1], qz = q[3 * qi + 2];
        float q2 = qx * qx + qy * qy + qz * qz;
        float bd[KNN]; int bi[KNN];
#pragma unroll
        for (int k = 0; k < KNN; k++) { bd[k] = BIGF; bi[k] = 0; }
        float thr = BIGF;
        int i = tid;
        for (; i + 1792 < M; i += 2048) {
            float4 p0 = rps[i];
            float4 p1 = rps[i + 256];
            float4 p2 = rps[i + 512];
            float4 p3 = rps[i + 768];
            float4 p4 = rps[i + 1024];
            float4 p5 = rps[i + 1280];
            float4 p6 = rps[i + 1536];
            float4 p7 = rps[i + 1792];
            float d0 = (q2 + p0.w) - 2.0f * (qx * p0.x + qy * p0.y + qz * p0.z);
            float d1 = (q2 + p1.w) - 2.0f * (qx * p1.x + qy * p1.y + qz * p1.z);
            float d2 = (q2 + p2.w) - 2.0f * (qx * p2.x + qy * p2.y + qz * p2.z);
            float d3 = (q2 + p3.w) - 2.0f * (qx * p3.x + qy * p3.y + qz * p3.z);
            float d4 = (q2 + p4.w) - 2.0f * (qx * p4.x + qy * p4.y + qz * p4.z);
            float d5 = (q2 + p5.w) - 2.0f * (qx * p5.x + qy * p5.y + qz * p5.z);
            float d6 = (q2 + p6.w) - 2.0f * (qx * p6.x + qy * p6.y + qz * p6.z);
            float d7 = (q2 + p7.w) - 2.0f * (qx * p7.x + qy * p7.y + qz * p7.z);
            if (d0 < thr) { insert8(d0, i,        bd, bi); thr = bd[0]; }
            if (d1 < thr) { insert8(d1, i + 256,  bd, bi); thr = bd[0]; }
            if (d2 < thr) { insert8(d2, i + 512,  bd, bi); thr = bd[0]; }
            if (d3 < thr) { insert8(d3, i + 768,  bd, bi); thr = bd[0]; }
            if (d4 < thr) { insert8(d4, i + 1024, bd, bi); thr = bd[0]; }
            if (d5 < thr) { insert8(d5, i + 1280, bd, bi); thr = bd[0]; }
            if (d6 < thr) { insert8(d6, i + 1536, bd, bi); thr = bd[0]; }
            if (d7 < thr) { insert8(d7, i + 1792, bd, bi); thr = bd[0]; }
        }
        for (; i < M; i += 256) {
            float4 p = rps[i];
            float d2 = (q2 + p.w) - 2.0f * (qx * p.x + qy * p.y + qz * p.z);
            if (d2 < thr) { insert8(d2, i, bd, bi); thr = bd[0]; }
        }
        // wave-internal bitonic merge: 64 disjoint sorted lists -> wave top-8.
        // Final merge MUST sort (insert8 below requires sorted-descending bd).
        merge_lists(bd, bi, 1, true);
        merge_lists(bd, bi, 2, true);
        merge_lists(bd, bi, 4, true);
        merge_lists(bd, bi, 8, true);
        merge_lists(bd, bi, 16, true);
        merge_lists(bd, bi, 32, true);
        if (lane == 0) {
#pragma unroll
            for (int k = 0; k < KNN; k++) { sd[wv][k] = bd[k]; si[wv][k] = bi[k]; }
        }
        __syncthreads();
        if (tid == 0) {
            for (int v = 1; v < 4; v++) {
#pragma unroll
                for (int k = 0; k < KNN; k++) insert8(sd[v][k], si[v][k], bd, bi);
            }
            float wsum = 0.f, ox = 0.f, oy = 0.f, oz = 0.f;
#pragma unroll
            for (int k = 0; k < KNN; k++) {
                float wgt = 1.0f / (fmaxf(bd[k], 0.0f) + EPSW);
                int j = sidx[bi[k]];
                wsum += wgt;
                ox += wgt * f[3 * j];
                oy += wgt * f[3 * j + 1];
                oz += wgt * f[3 * j + 2];
            }
            float invw = 1.0f / wsum;
            out[3 * qi]     = ox * invw;
            out[3 * qi + 1] = oy * invw;
            out[3 * qi + 2] = oz * invw;
        }
        __syncthreads();
    }
}

// ---------- fallback (ws too small): fused single-pass brute force ----------
__global__ __launch_bounds__(BLOCK) void knn_fused(
    const float* __restrict__ q, const float* __restrict__ r,
    const float* __restrict__ f, float* __restrict__ out, int N, int M) {
    __shared__ float4 lds[TILE];
    int qi = blockIdx.x * BLOCK + threadIdx.x;
    float qx = 0.f, qy = 0.f, qz = 0.f, q2 = 0.f;
    if (qi < N) {
        qx = q[3 * qi]; qy = q[3 * qi + 1]; qz = q[3 * qi + 2];
        q2 = qx * qx + qy * qy + qz * qz;
    }
    float bd[KNN]; int bi[KNN];
#pragma unroll
    for (int k = 0; k < KNN; k++) { bd[k] = BIGF; bi[k] = 0; }
    for (int tb = 0; tb < M; tb += TILE) {
        int cnt = min(TILE, M - tb);
        for (int i = threadIdx.x; i < cnt; i += BLOCK) {
            int j = tb + i;
            float rx = r[3 * j], ry = r[3 * j + 1], rz = r[3 * j + 2];
            lds[i] = make_float4(rx, ry, rz, rx * rx + ry * ry + rz * rz);
        }
        __syncthreads();
        for (int i = 0; i < cnt; i++) {
            float4 p = lds[i];
            float d2 = (q2 + p.w) - 2.0f * (qx * p.x + qy * p.y + qz * p.z);
            insert8(d2, tb + i, bd, bi);
        }
        __syncthreads();
    }
    if (qi < N) {
        float wsum = 0.f, ox = 0.f, oy = 0.f, oz = 0.f;
#pragma unroll
        for (int k = 0; k < KNN; k++) {
            float w = 1.0f / (fmaxf(bd[k], 0.0f) + EPSW);
            int j = bi[k];
            ox += w * f[3 * j];
            oy += w * f[3 * j + 1];
            oz += w * f[3 * j + 2];
        }
        float inv = 1.0f / wsum;
        out[3 * qi]     = ox * inv;
        out[3 * qi + 1] = oy * inv;
        out[3 * qi + 2] = oz * inv;
    }
}

extern "C" void kernel_launch(void* const* d_in, const int* in_sizes, int n_in,
                              void* d_out, int out_size, void* d_ws, size_t ws_size,
                              hipStream_t stream) {
    const float* q = (const float*)d_in[0];
    const float* r = (const float*)d_in[1];
    const float* f = (const float*)d_in[2];
    float* out = (float*)d_out;
    int N = in_sizes[0] / 3;
    int M = in_sizes[1] / 3;

    // workspace layout (256B-aligned slots), ~1.8 MB total
    size_t off = 0;
    auto take = [&](size_t b) { size_t o = off; off += (b + 255) & ~(size_t)255; return o; };
    size_t o_rps  = take((size_t)M * 16);
    size_t o_qps  = take((size_t)N * 16);
    size_t o_sidx = take((size_t)M * 4);
    size_t o_rcid = take((size_t)M * 4);
    size_t o_qcid = take((size_t)N * 4);
    size_t o_qord = take((size_t)N * 4);
    size_t o_rst  = take((size_t)(NC + 1) * 4);
    size_t o_qst  = take((size_t)(NC + 1) * 4);
    size_t o_rcur = take((size_t)NC * 4);   // } contiguous zero region:
    size_t o_qcur = take((size_t)NC * 4);   // } rcur, qcur, pcnt
    size_t o_pcnt = take(4);                // }
    size_t o_pend = take((size_t)N * 4);
    size_t o_bb   = take(64);

    int grid_x = (N + BLOCK - 1) / BLOCK;
    if (off <= ws_size) {
        char* w = (char*)d_ws;
        float4* rps   = (float4*)(w + o_rps);
        float4* qps   = (float4*)(w + o_qps);
        int* sidx     = (int*)(w + o_sidx);
        int* rcid     = (int*)(w + o_rcid);
        int* qcid     = (int*)(w + o_qcid);
        int* qorder   = (int*)(w + o_qord);
        int* rstart   = (int*)(w + o_rst);
        int* qstart   = (int*)(w + o_qst);
        int* rcur     = (int*)(w + o_rcur);
        int* qcur     = (int*)(w + o_qcur);
        int* pcnt     = (int*)(w + o_pcnt);
        int* pend     = (int*)(w + o_pend);
        unsigned* bbw = (unsigned*)(w + o_bb);

        // single init memset: all 6 bbox words -> 0xFFFFFFFF (min-encoded)
        hipMemsetAsync(w + o_bb, 0xFF, 24, stream);

        int zcount = (int)((o_pcnt + 4 - o_rcur) / 4);   // rcur+qcur+pcnt (contiguous)
        int g_all = (M + N + 255) / 256;
        bbox_zero<<<64, 256, 0, stream>>>(r, M, bbw, rcur, zcount);
        hist2<<<g_all, 256, 0, stream>>>(r, q, M, N, bbw, rcid, qcid, rcur, qcur);
        scan2<<<2, 1024, 0, stream>>>(rcur, rstart, qcur, qstart);
        scatter2<<<g_all, 256, 0, stream>>>(r, q, M, N, rcid, qcid, rcur, qcur,
                                            rps, sidx, qps, qorder);
        int g_p1 = (int)(((size_t)N * 4 + 255) / 256);
        knn_pass1<<<g_p1, 256, 0, stream>>>(rps, rstart, qps, qorder, sidx, f, bbw, out,
                                            pend, pcnt, N);
        knn_pass2<<<512, 256, 0, stream>>>(rps, pend, pcnt, q, sidx, f, out, M);
    } else {
        knn_fused<<<grid_x, BLOCK, 0, stream>>>(q, r, f, out, N, M);
    }
}

// Round 15
// 196.756 us; speedup vs baseline: 1.1348x; 1.1348x over previous
//
#include <hip/hip_runtime.h>

#define KNN    8
#define BLOCK  256
#define TILE   2048
#define GD     32              // grid cells per axis
#define NC     (GD*GD*GD)      // 32768 cells
#define EPSW   1e-8f
#define BIGF   3.4e38f

// Sorted-descending top-8 insert; all indices compile-time -> stays in VGPRs.
// REQUIRES bd sorted descending (bd[0] = current max); preserves that invariant.
__device__ __forceinline__ void insert8(float d2, int j, float bd[KNN], int bi[KNN]) {
    if (d2 < bd[0]) {
        bd[0] = d2; bi[0] = j;
#pragma unroll
        for (int t = 0; t < KNN - 1; t++) {
            if (bd[t] < bd[t + 1]) {
                float td = bd[t]; bd[t] = bd[t + 1]; bd[t + 1] = td;
                int   ti = bi[t]; bi[t] = bi[t + 1]; bi[t + 1] = ti;
            }
        }
    }
}

// Compare-exchange, descending (a keeps max), with index payload.
__device__ __forceinline__ void ced(float& a, int& ai, float& b, int& bi) {
    if (a < b) { float t = a; a = b; b = t; int ti = ai; ai = bi; bi = ti; }
}
// Sort a bitonic 8-seq descending (3 half-cleaner stages), with payload.
__device__ __forceinline__ void sort8_desc(float d[KNN], int ix[KNN]) {
    ced(d[0],ix[0],d[4],ix[4]); ced(d[1],ix[1],d[5],ix[5]);
    ced(d[2],ix[2],d[6],ix[6]); ced(d[3],ix[3],d[7],ix[7]);
    ced(d[0],ix[0],d[2],ix[2]); ced(d[1],ix[1],d[3],ix[3]);
    ced(d[4],ix[4],d[6],ix[6]); ced(d[5],ix[5],d[7],ix[7]);
    ced(d[0],ix[0],d[1],ix[1]); ced(d[2],ix[2],d[3],ix[3]);
    ced(d[4],ix[4],d[5],ix[5]); ced(d[6],ix[6],d[7],ix[7]);
}
// Merge with partner lane (xor mask): keep the 8 smallest of my-desc-sorted
// list and partner's desc-sorted list (bitonic half-cleaner: C[i]=min(A[i],B[7-i])).
// Both partners compute the identical merged list. Result bitonic; sort if chaining
// OR if insert8 will be applied afterwards (insert8 requires sorted input!).
__device__ __forceinline__ void merge_lists(float bd[KNN], int bi[KNN], int mask, bool sort_after) {
    float pd[KNN]; int pi[KNN];
#pragma unroll
    for (int j = 0; j < KNN; j++) { pd[j] = __shfl_xor(bd[j], mask); pi[j] = __shfl_xor(bi[j], mask); }
#pragma unroll
    for (int j = 0; j < KNN; j++) {
        if (pd[KNN - 1 - j] < bd[j]) { bd[j] = pd[KNN - 1 - j]; bi[j] = pi[KNN - 1 - j]; }
    }
    if (sort_after) sort8_desc(bd, bi);
}
// Exact 8th-smallest over the 4 lanes of a quad (distances only, temps; does
// NOT modify bd). All 4 lanes return the same value.
__device__ __forceinline__ float merged_thr4(const float bd[KNN]) {
    float c[KNN], p[KNN];
#pragma unroll
    for (int j = 0; j < KNN; j++) c[j] = bd[j];
#pragma unroll
    for (int j = 0; j < KNN; j++) p[j] = __shfl_xor(c[j], 1);
#pragma unroll
    for (int j = 0; j < KNN; j++) c[j] = fminf(c[j], p[KNN - 1 - j]);
    // sort bitonic desc (no payload)
    {
        float mx, mn;
        mx = fmaxf(c[0],c[4]); mn = fminf(c[0],c[4]); c[0]=mx; c[4]=mn;
        mx = fmaxf(c[1],c[5]); mn = fminf(c[1],c[5]); c[1]=mx; c[5]=mn;
        mx = fmaxf(c[2],c[6]); mn = fminf(c[2],c[6]); c[2]=mx; c[6]=mn;
        mx = fmaxf(c[3],c[7]); mn = fminf(c[3],c[7]); c[3]=mx; c[7]=mn;
        mx = fmaxf(c[0],c[2]); mn = fminf(c[0],c[2]); c[0]=mx; c[2]=mn;
        mx = fmaxf(c[1],c[3]); mn = fminf(c[1],c[3]); c[1]=mx; c[3]=mn;
        mx = fmaxf(c[4],c[6]); mn = fminf(c[4],c[6]); c[4]=mx; c[6]=mn;
        mx = fmaxf(c[5],c[7]); mn = fminf(c[5],c[7]); c[5]=mx; c[7]=mn;
        mx = fmaxf(c[0],c[1]); mn = fminf(c[0],c[1]); c[0]=mx; c[1]=mn;
        mx = fmaxf(c[2],c[3]); mn = fminf(c[2],c[3]); c[2]=mx; c[3]=mn;
        mx = fmaxf(c[4],c[5]); mn = fminf(c[4],c[5]); c[4]=mx; c[5]=mn;
        mx = fmaxf(c[6],c[7]); mn = fminf(c[6],c[7]); c[6]=mx; c[7]=mn;
    }
#pragma unroll
    for (int j = 0; j < KNN; j++) p[j] = __shfl_xor(c[j], 2);
#pragma unroll
    for (int j = 0; j < KNN; j++) c[j] = fminf(c[j], p[KNN - 1 - j]);
    float m = c[0];
#pragma unroll
    for (int j = 1; j < KNN; j++) m = fmaxf(m, c[j]);
    return m;
}

// Order-preserving float <-> uint for atomic min.
__device__ __forceinline__ unsigned fenc(float f) {
    unsigned u = __float_as_uint(f);
    return (u & 0x80000000u) ? ~u : (u | 0x80000000u);
}
__device__ __forceinline__ float fdec(unsigned e) {
    unsigned u = (e & 0x80000000u) ? (e ^ 0x80000000u) : ~e;
    return __uint_as_float(u);
}

// bbw[0..2] = enc(min), bbw[3..5] = enc(-max)  -> ALL init to 0xFFFFFFFF,
// ALL updated with atomicMin (one memset, one atomic op type).
__device__ __forceinline__ void load_bb(const unsigned* __restrict__ bbw,
                                        float mn[3], float inv[3], float& hmin) {
    hmin = BIGF;
#pragma unroll
    for (int a = 0; a < 3; a++) {
        float lo = fdec(bbw[a]), hi = -fdec(bbw[3 + a]);
        float w = fmaxf(hi - lo, 1e-9f);
        mn[a] = lo;
        inv[a] = (float)GD / w;
        hmin = fminf(hmin, w / (float)GD);
    }
}

__device__ __forceinline__ int cell_clamp(int c) {
    return c < 0 ? 0 : (c > GD - 1 ? GD - 1 : c);
}

// ---------------- grid build ----------------

// Fused: zero counter region (rcur,qcur,pcnt) + multi-block bbox over refs.
__global__ __launch_bounds__(256) void bbox_zero(const float* __restrict__ r, int M,
                                                 unsigned* __restrict__ bbw,
                                                 int* __restrict__ zbase, int zcount) {
    int idx = blockIdx.x * 256 + threadIdx.x;
    for (int j = idx; j < zcount; j += gridDim.x * 256) zbase[j] = 0;
    float mn0 = BIGF, mn1 = BIGF, mn2 = BIGF;
    float mx0 = -BIGF, mx1 = -BIGF, mx2 = -BIGF;
    for (int j = idx; j < M; j += gridDim.x * 256) {
        float x = r[3 * j], y = r[3 * j + 1], z = r[3 * j + 2];
        mn0 = fminf(mn0, x); mx0 = fmaxf(mx0, x);
        mn1 = fminf(mn1, y); mx1 = fmaxf(mx1, y);
        mn2 = fminf(mn2, z); mx2 = fmaxf(mx2, z);
    }
#pragma unroll
    for (int o = 32; o > 0; o >>= 1) {
        mn0 = fminf(mn0, __shfl_xor(mn0, o));
        mn1 = fminf(mn1, __shfl_xor(mn1, o));
        mn2 = fminf(mn2, __shfl_xor(mn2, o));
        mx0 = fmaxf(mx0, __shfl_xor(mx0, o));
        mx1 = fmaxf(mx1, __shfl_xor(mx1, o));
        mx2 = fmaxf(mx2, __shfl_xor(mx2, o));
    }
    if ((threadIdx.x & 63) == 0) {
        atomicMin(bbw + 0, fenc(mn0)); atomicMin(bbw + 1, fenc(mn1)); atomicMin(bbw + 2, fenc(mn2));
        atomicMin(bbw + 3, fenc(-mx0)); atomicMin(bbw + 4, fenc(-mx1)); atomicMin(bbw + 5, fenc(-mx2));
    }
}

// Histogram refs AND queries in one dispatch (items 0..M-1 = refs, M..M+N-1 = queries).
__global__ __launch_bounds__(256) void hist2(const float* __restrict__ r,
                                             const float* __restrict__ q,
                                             int M, int N, const unsigned* __restrict__ bbw,
                                             int* __restrict__ rcid, int* __restrict__ qcid,
                                             int* __restrict__ rcnt, int* __restrict__ qcnt) {
    float mn[3], inv[3], hmin;
    load_bb(bbw, mn, inv, hmin);
    int i = blockIdx.x * 256 + threadIdx.x;
    if (i < M) {
        int cx = cell_clamp((int)((r[3 * i]     - mn[0]) * inv[0]));
        int cy = cell_clamp((int)((r[3 * i + 1] - mn[1]) * inv[1]));
        int cz = cell_clamp((int)((r[3 * i + 2] - mn[2]) * inv[2]));
        int cid = (cz * GD + cy) * GD + cx;
        rcid[i] = cid;
        atomicAdd(rcnt + cid, 1);
    } else if (i < M + N) {
        int j = i - M;
        int cx = cell_clamp((int)((q[3 * j]     - mn[0]) * inv[0]));
        int cy = cell_clamp((int)((q[3 * j + 1] - mn[1]) * inv[1]));
        int cz = cell_clamp((int)((q[3 * j + 2] - mn[2]) * inv[2]));
        int cid = (cz * GD + cy) * GD + cx;
        qcid[j] = cid;
        atomicAdd(qcnt + cid, 1);
    }
}

// Exclusive scan of NC cell counts; block 0 -> refs, block 1 -> queries.
__global__ __launch_bounds__(1024) void scan2(int* __restrict__ rcnt, int* __restrict__ rstart,
                                              int* __restrict__ qcnt, int* __restrict__ qstart) {
    int* cnt = (blockIdx.x == 0) ? rcnt : qcnt;
    int* st  = (blockIdx.x == 0) ? rstart : qstart;
    __shared__ int part[1024];
    int t = threadIdx.x;
    int base = t * 32;
    int s = 0;
#pragma unroll
    for (int k = 0; k < 32; k++) s += cnt[base + k];
    part[t] = s;
    __syncthreads();
    for (int off = 1; off < 1024; off <<= 1) {
        int v = (t >= off) ? part[t - off] : 0;
        __syncthreads();
        part[t] += v;
        __syncthreads();
    }
    int run = part[t] - s;
#pragma unroll
    for (int k = 0; k < 32; k++) {
        int c = cnt[base + k];
        st[base + k] = run;
        cnt[base + k] = run;         // cursor = start
        run += c;
    }
    if (t == 1023) st[NC] = run;
}

// Scatter refs into cell-sorted packed float4 (x,y,z,|r|^2) + orig-index map;
// scatter queries into cell-sorted packed float4 (x,y,z,|q|^2) + orig-index
// order (PRE-GATHER: pass1 then reads qps[g] coalesced, no scattered q loads).
__global__ __launch_bounds__(256) void scatter2(const float* __restrict__ r,
                                                const float* __restrict__ q, int M, int N,
                                                const int* __restrict__ rcid,
                                                const int* __restrict__ qcid,
                                                int* __restrict__ rcur, int* __restrict__ qcur,
                                                float4* __restrict__ rps, int* __restrict__ sidx,
                                                float4* __restrict__ qps, int* __restrict__ qorder) {
    int i = blockIdx.x * 256 + threadIdx.x;
    if (i < M) {
        int pos = atomicAdd(rcur + rcid[i], 1);
        float x = r[3 * i], y = r[3 * i + 1], z = r[3 * i + 2];
        rps[pos] = make_float4(x, y, z, x * x + y * y + z * z);
        sidx[pos] = i;
    } else if (i < M + N) {
        int j = i - M;
        int pos = atomicAdd(qcur + qcid[j], 1);
        float x = q[3 * j], y = q[3 * j + 1], z = q[3 * j + 2];
        qps[pos] = make_float4(x, y, z, x * x + y * y + z * z);
        qorder[pos] = j;
    }
}

// Scan a Chebyshev shell at ring R (quad-cooperative: this lane takes points
// ii = s+sub, s+sub+4, ...). x-contiguous rows collapse to one range scan.
__device__ __forceinline__ void scan_shell(
    int R, int cx, int cy, int cz, int sub,
    const float4* __restrict__ rps, const int* __restrict__ rstart,
    float qx, float qy, float qz, float q2,
    float bd[KNN], int bi[KNN], float& thr) {
    for (int dz = -R; dz <= R; ++dz) {
        int z = cz + dz;
        if ((unsigned)z >= GD) continue;
        for (int dy = -R; dy <= R; ++dy) {
            int y = cy + dy;
            if ((unsigned)y >= GD) continue;
            int rowb = (z * GD + y) * GD;
            if (dz == -R || dz == R || dy == -R || dy == R) {
                int x0 = max(cx - R, 0), x1 = min(cx + R, GD - 1);
                int s = rstart[rowb + x0], e = rstart[rowb + x1 + 1];
                for (int ii = s + sub; ii < e; ii += 4) {
                    float4 p = rps[ii];
                    float d2 = (q2 + p.w) - 2.0f * (qx * p.x + qy * p.y + qz * p.z);
                    if (d2 < thr) { insert8(d2, ii, bd, bi); thr = bd[0]; }
                }
            } else {
                int xl = cx - R, xr = cx + R;
                if (xl >= 0) {
                    int s = rstart[rowb + xl], e = rstart[rowb + xl + 1];
                    for (int ii = s + sub; ii < e; ii += 4) {
                        float4 p = rps[ii];
                        float d2 = (q2 + p.w) - 2.0f * (qx * p.x + qy * p.y + qz * p.z);
                        if (d2 < thr) { insert8(d2, ii, bd, bi); thr = bd[0]; }
                    }
                }
                if (xr < GD) {
                    int s = rstart[rowb + xr], e = rstart[rowb + xr + 1];
                    for (int ii = s + sub; ii < e; ii += 4) {
                        float4 p = rps[ii];
                        float d2 = (q2 + p.w) - 2.0f * (qx * p.x + qy * p.y + qz * p.z);
                        if (d2 < thr) { insert8(d2, ii, bd, bi); thr = bd[0]; }
                    }
                }
            }
        }
    }
}

// ---------------- pass 1: 4 lanes per query, rings 0..2 ONLY ----------------
// Lanes split each point stream mod 4 (disjoint -> duplicate-free union).
// Termination bound: EXACT merged 8th-smallest over the quad (merged_thr4).
// Query coords come from the PRE-GATHERED qps[] (coalesced). After rings 0..R,
// unscanned cells are >= R*hmin away (valid for bbox-clamped queries since
// refs are never clamped). Ring 3 is DELIBERATELY NOT scanned here: queries
// not terminated by the ring-2 bound (~15-25%) are the latency-dominating
// stragglers; they go to pass 2, which at 4096 blocks has the occupancy
// headroom to absorb them.
__global__ __launch_bounds__(256) void knn_pass1(
    const float4* __restrict__ rps, const int* __restrict__ rstart,
    const float4* __restrict__ qps, const int* __restrict__ qorder,
    const int* __restrict__ sidx, const float* __restrict__ f,
    const unsigned* __restrict__ bbw, float* __restrict__ out,
    int* __restrict__ pend, int* __restrict__ pcnt, int N) {
    int t = blockIdx.x * 256 + threadIdx.x;
    int g = t >> 2;                 // query-group id
    int sub = t & 3;
    if (g >= N) return;
    int qi = qorder[g];             // independent load; needed only at the end
    float4 qp = qps[g];             // coalesced/broadcast 16B
    float qx = qp.x, qy = qp.y, qz = qp.z, q2 = qp.w;
    float mn[3], inv[3], hmin;
    load_bb(bbw, mn, inv, hmin);
    int cx = cell_clamp((int)((qx - mn[0]) * inv[0]));
    int cy = cell_clamp((int)((qy - mn[1]) * inv[1]));
    int cz = cell_clamp((int)((qz - mn[2]) * inv[2]));

    float bd[KNN]; int bi[KNN];
#pragma unroll
    for (int k = 0; k < KNN; k++) { bd[k] = BIGF; bi[k] = 0; }
    float thr = BIGF;

    // --- rings 0..1 as nine full rows; all 9 range pairs hoisted (independent loads) ---
    int rs[9], re[9];
#pragma unroll
    for (int dz = -1; dz <= 1; dz++) {
#pragma unroll
        for (int dy = -1; dy <= 1; dy++) {
            int k = (dz + 1) * 3 + (dy + 1);
            int z = cz + dz, y = cy + dy;
            if ((unsigned)z >= GD || (unsigned)y >= GD) { rs[k] = 0; re[k] = 0; }
            else {
                int rowb = (z * GD + y) * GD;
                int x0 = max(cx - 1, 0), x1 = min(cx + 1, GD - 1);
                rs[k] = rstart[rowb + x0]; re[k] = rstart[rowb + x1 + 1];
            }
        }
    }
#pragma unroll
    for (int k = 0; k < 9; k++) {
        for (int ii = rs[k] + sub; ii < re[k]; ii += 4) {
            float4 p = rps[ii];
            float d2 = (q2 + p.w) - 2.0f * (qx * p.x + qy * p.y + qz * p.z);
            if (d2 < thr) { insert8(d2, ii, bd, bi); thr = bd[0]; }
        }
    }
    float mthr = merged_thr4(bd);
    thr = fminf(thr, mthr);
    bool done = (mthr <= hmin * hmin);

    if (!done) {
        scan_shell(2, cx, cy, cz, sub, rps, rstart, qx, qy, qz, q2, bd, bi, thr);
        mthr = merged_thr4(bd);
        done = (mthr <= 4.0f * hmin * hmin);
    }

    if (!done) {
        if (sub == 0) { int pos = atomicAdd(pcnt, 1); pend[pos] = qi; }
        return;
    }

    // exact merge of the quad's 4 disjoint lists -> global top-8 (order-free for IDW)
    merge_lists(bd, bi, 1, true);
    merge_lists(bd, bi, 2, false);
    if (sub == 0) {
        float wsum = 0.f, ox = 0.f, oy = 0.f, oz = 0.f;
#pragma unroll
        for (int k = 0; k < KNN; k++) {
            float w = 1.0f / (fmaxf(bd[k], 0.0f) + EPSW);
            int j = sidx[bi[k]];
            wsum += w;
            ox += w * f[3 * j];
            oy += w * f[3 * j + 1];
            oz += w * f[3 * j + 2];
        }
        float invw = 1.0f / wsum;
        out[3 * qi]     = ox * invw;
        out[3 * qi + 1] = oy * invw;
        out[3 * qi + 2] = oz * invw;
    }
}

// ---------------- pass 2: BLOCK-per-query exact brute force ----------------
// 256 threads share one pending query: each scans M/256 candidates 8-deep
// pipelined, wave-internal bitonic merge (FINAL MERGE SORTED: insert8 follows),
// 4-entry cross-wave LDS merge by tid 0. Launched with 4096 blocks: grid-
// stride w-loop; excess blocks exit after reading cnt.
__global__ __launch_bounds__(256) void knn_pass2(
    const float4* __restrict__ rps, const int* __restrict__ pend,
    const int* __restrict__ pcnt, const float* __restrict__ q,
    const int* __restrict__ sidx, const float* __restrict__ f,
    float* __restrict__ out, int M) {
    __shared__ float sd[4][KNN];
    __shared__ int   si[4][KNN];
    int tid = threadIdx.x;
    int lane = tid & 63, wv = tid >> 6;
    int cnt = *pcnt;
    for (int w = blockIdx.x; w < cnt; w += gridDim.x) {
        int qi = pend[w];
        float qx = q[3 * qi], qy = q[3 * qi + 1], qz = q[3 * qi + 2];
        float q2 = qx * qx + qy * qy + qz * qz;
        float bd[KNN]; int bi[KNN];
#pragma unroll
        for (int k = 0; k < KNN; k++) { bd[k] = BIGF; bi[k] = 0; }
        float thr = BIGF;
        int i = tid;
        for (; i + 1792 < M; i += 2048) {
            float4 p0 = rps[i];
            float4 p1 = rps[i + 256];
            float4 p2 = rps[i + 512];
            float4 p3 = rps[i + 768];
            float4 p4 = rps[i + 1024];
            float4 p5 = rps[i + 1280];
            float4 p6 = rps[i + 1536];
            float4 p7 = rps[i + 1792];
            float d0 = (q2 + p0.w) - 2.0f * (qx * p0.x + qy * p0.y + qz * p0.z);
            float d1 = (q2 + p1.w) - 2.0f * (qx * p1.x + qy * p1.y + qz * p1.z);
            float d2 = (q2 + p2.w) - 2.0f * (qx * p2.x + qy * p2.y + qz * p2.z);
            float d3 = (q2 + p3.w) - 2.0f * (qx * p3.x + qy * p3.y + qz * p3.z);
            float d4 = (q2 + p4.w) - 2.0f * (qx * p4.x + qy * p4.y + qz * p4.z);
            float d5 = (q2 + p5.w) - 2.0f * (qx * p5.x + qy * p5.y + qz * p5.z);
            float d6 = (q2 + p6.w) - 2.0f * (qx * p6.x + qy * p6.y + qz * p6.z);
            float d7 = (q2 + p7.w) - 2.0f * (qx * p7.x + qy * p7.y + qz * p7.z);
            if (d0 < thr) { insert8(d0, i,        bd, bi); thr = bd[0]; }
            if (d1 < thr) { insert8(d1, i + 256,  bd, bi); thr = bd[0]; }
            if (d2 < thr) { insert8(d2, i + 512,  bd, bi); thr = bd[0]; }
            if (d3 < thr) { insert8(d3, i + 768,  bd, bi); thr = bd[0]; }
            if (d4 < thr) { insert8(d4, i + 1024, bd, bi); thr = bd[0]; }
            if (d5 < thr) { insert8(d5, i + 1280, bd, bi); thr = bd[0]; }
            if (d6 < thr) { insert8(d6, i + 1536, bd, bi); thr = bd[0]; }
            if (d7 < thr) { insert8(d7, i + 1792, bd, bi); thr = bd[0]; }
        }
        for (; i < M; i += 256) {
            float4 p = rps[i];
            float d2 = (q2 + p.w) - 2.0f * (qx * p.x + qy * p.y + qz * p.z);
            if (d2 < thr) { insert8(d2, i, bd, bi); thr = bd[0]; }
        }
        // wave-internal bitonic merge: 64 disjoint sorted lists -> wave top-8.
        // Final merge MUST sort (insert8 below requires sorted-descending bd).
        merge_lists(bd, bi, 1, true);
        merge_lists(bd, bi, 2, true);
        merge_lists(bd, bi, 4, true);
        merge_lists(bd, bi, 8, true);
        merge_lists(bd, bi, 16, true);
        merge_lists(bd, bi, 32, true);
        if (lane == 0) {
#pragma unroll
            for (int k = 0; k < KNN; k++) { sd[wv][k] = bd[k]; si[wv][k] = bi[k]; }
        }
        __syncthreads();
        if (tid == 0) {
            for (int v = 1; v < 4; v++) {
#pragma unroll
                for (int k = 0; k < KNN; k++) insert8(sd[v][k], si[v][k], bd, bi);
            }
            float wsum = 0.f, ox = 0.f, oy = 0.f, oz = 0.f;
#pragma unroll
            for (int k = 0; k < KNN; k++) {
                float wgt = 1.0f / (fmaxf(bd[k], 0.0f) + EPSW);
                int j = sidx[bi[k]];
                wsum += wgt;
                ox += wgt * f[3 * j];
                oy += wgt * f[3 * j + 1];
                oz += wgt * f[3 * j + 2];
            }
            float invw = 1.0f / wsum;
            out[3 * qi]     = ox * invw;
            out[3 * qi + 1] = oy * invw;
            out[3 * qi + 2] = oz * invw;
        }
        __syncthreads();
    }
}

// ---------- fallback (ws too small): fused single-pass brute force ----------
__global__ __launch_bounds__(BLOCK) void knn_fused(
    const float* __restrict__ q, const float* __restrict__ r,
    const float* __restrict__ f, float* __restrict__ out, int N, int M) {
    __shared__ float4 lds[TILE];
    int qi = blockIdx.x * BLOCK + threadIdx.x;
    float qx = 0.f, qy = 0.f, qz = 0.f, q2 = 0.f;
    if (qi < N) {
        qx = q[3 * qi]; qy = q[3 * qi + 1]; qz = q[3 * qi + 2];
        q2 = qx * qx + qy * qy + qz * qz;
    }
    float bd[KNN]; int bi[KNN];
#pragma unroll
    for (int k = 0; k < KNN; k++) { bd[k] = BIGF; bi[k] = 0; }
    for (int tb = 0; tb < M; tb += TILE) {
        int cnt = min(TILE, M - tb);
        for (int i = threadIdx.x; i < cnt; i += BLOCK) {
            int j = tb + i;
            float rx = r[3 * j], ry = r[3 * j + 1], rz = r[3 * j + 2];
            lds[i] = make_float4(rx, ry, rz, rx * rx + ry * ry + rz * rz);
        }
        __syncthreads();
        for (int i = 0; i < cnt; i++) {
            float4 p = lds[i];
            float d2 = (q2 + p.w) - 2.0f * (qx * p.x + qy * p.y + qz * p.z);
            insert8(d2, tb + i, bd, bi);
        }
        __syncthreads();
    }
    if (qi < N) {
        float wsum = 0.f, ox = 0.f, oy = 0.f, oz = 0.f;
#pragma unroll
        for (int k = 0; k < KNN; k++) {
            float w = 1.0f / (fmaxf(bd[k], 0.0f) + EPSW);
            int j = bi[k];
            ox += w * f[3 * j];
            oy += w * f[3 * j + 1];
            oz += w * f[3 * j + 2];
        }
        float inv = 1.0f / wsum;
        out[3 * qi]     = ox * inv;
        out[3 * qi + 1] = oy * inv;
        out[3 * qi + 2] = oz * inv;
    }
}

extern "C" void kernel_launch(void* const* d_in, const int* in_sizes, int n_in,
                              void* d_out, int out_size, void* d_ws, size_t ws_size,
                              hipStream_t stream) {
    const float* q = (const float*)d_in[0];
    const float* r = (const float*)d_in[1];
    const float* f = (const float*)d_in[2];
    float* out = (float*)d_out;
    int N = in_sizes[0] / 3;
    int M = in_sizes[1] / 3;

    // workspace layout (256B-aligned slots), ~1.8 MB total
    size_t off = 0;
    auto take = [&](size_t b) { size_t o = off; off += (b + 255) & ~(size_t)255; return o; };
    size_t o_rps  = take((size_t)M * 16);
    size_t o_qps  = take((size_t)N * 16);
    size_t o_sidx = take((size_t)M * 4);
    size_t o_rcid = take((size_t)M * 4);
    size_t o_qcid = take((size_t)N * 4);
    size_t o_qord = take((size_t)N * 4);
    size_t o_rst  = take((size_t)(NC + 1) * 4);
    size_t o_qst  = take((size_t)(NC + 1) * 4);
    size_t o_rcur = take((size_t)NC * 4);   // } contiguous zero region:
    size_t o_qcur = take((size_t)NC * 4);   // } rcur, qcur, pcnt
    size_t o_pcnt = take(4);                // }
    size_t o_pend = take((size_t)N * 4);
    size_t o_bb   = take(64);

    int grid_x = (N + BLOCK - 1) / BLOCK;
    if (off <= ws_size) {
        char* w = (char*)d_ws;
        float4* rps   = (float4*)(w + o_rps);
        float4* qps   = (float4*)(w + o_qps);
        int* sidx     = (int*)(w + o_sidx);
        int* rcid     = (int*)(w + o_rcid);
        int* qcid     = (int*)(w + o_qcid);
        int* qorder   = (int*)(w + o_qord);
        int* rstart   = (int*)(w + o_rst);
        int* qstart   = (int*)(w + o_qst);
        int* rcur     = (int*)(w + o_rcur);
        int* qcur     = (int*)(w + o_qcur);
        int* pcnt     = (int*)(w + o_pcnt);
        int* pend     = (int*)(w + o_pend);
        unsigned* bbw = (unsigned*)(w + o_bb);

        // single init memset: all 6 bbox words -> 0xFFFFFFFF (min-encoded)
        hipMemsetAsync(w + o_bb, 0xFF, 24, stream);

        int zcount = (int)((o_pcnt + 4 - o_rcur) / 4);   // rcur+qcur+pcnt (contiguous)
        int g_all = (M + N + 255) / 256;
        bbox_zero<<<64, 256, 0, stream>>>(r, M, bbw, rcur, zcount);
        hist2<<<g_all, 256, 0, stream>>>(r, q, M, N, bbw, rcid, qcid, rcur, qcur);
        scan2<<<2, 1024, 0, stream>>>(rcur, rstart, qcur, qstart);
        scatter2<<<g_all, 256, 0, stream>>>(r, q, M, N, rcid, qcid, rcur, qcur,
                                            rps, sidx, qps, qorder);
        int g_p1 = (int)(((size_t)N * 4 + 255) / 256);
        knn_pass1<<<g_p1, 256, 0, stream>>>(rps, rstart, qps, qorder, sidx, f, bbw, out,
                                            pend, pcnt, N);
        knn_pass2<<<4096, 256, 0, stream>>>(rps, pend, pcnt, q, sidx, f, out, M);
    } else {
        knn_fused<<<grid_x, BLOCK, 0, stream>>>(q, r, f, out, N, M);
    }
}